// Round 1
// baseline (1868.219 us; speedup 1.0000x reference)
//
#include <hip/hip_runtime.h>

typedef __attribute__((ext_vector_type(4))) float f32x4;
typedef __attribute__((ext_vector_type(8))) __bf16 bf16x8;
typedef __attribute__((ext_vector_type(8))) unsigned short u16x8;
typedef unsigned short u16;
typedef unsigned int u32;

#define B_ 2
#define S_ 2048
#define D_ 4096
#define H_ 32
#define KVH_ 8
#define HD_ 128
#define SW_ 4096
#define SCALE_ 0.08838834764831845f

__device__ __forceinline__ u16 f2bf(float f) {
  union { float f; u32 u; } v; v.f = f;
  u32 r = v.u + 0x7FFF + ((v.u >> 16) & 1);
  return (u16)(r >> 16);
}
__device__ __forceinline__ float bf2f(u16 h) {
  union { u32 u; float f; } v; v.u = ((u32)h) << 16;
  return v.f;
}
__device__ __forceinline__ void gload16(const void* g, void* l) {
  __builtin_amdgcn_global_load_lds(
      (__attribute__((address_space(1))) u32*)(uintptr_t)g,
      (__attribute__((address_space(3))) u32*)l, 16, 0, 0);
}

// ---------------- elementwise f32 -> bf16 (8 elems/thread) ----------------
__global__ __launch_bounds__(256) void k_f32_to_bf16(const float* __restrict__ in,
                                                     u16* __restrict__ out) {
  long i = (long)(blockIdx.x * 256 + threadIdx.x) * 8;
  f32x4 a = *(const f32x4*)(in + i);
  f32x4 b = *(const f32x4*)(in + i + 4);
  u16x8 o;
  o[0] = f2bf(a[0]); o[1] = f2bf(a[1]); o[2] = f2bf(a[2]); o[3] = f2bf(a[3]);
  o[4] = f2bf(b[0]); o[5] = f2bf(b[1]); o[6] = f2bf(b[2]); o[7] = f2bf(b[3]);
  *(u16x8*)(out + i) = o;
}

// ---------------- weight transpose: [R][C] f32 -> [C][R] bf16 ----------------
__global__ __launch_bounds__(256) void k_transpose_w(const float* __restrict__ in,
                                                     u16* __restrict__ out, int R, int C) {
  __shared__ u16 tile[64][72];
  int t = threadIdx.x;
  int c0 = blockIdx.x * 64, r0 = blockIdx.y * 64;
  int rr = t >> 2, cc = (t & 3) << 4;
  const float* p = in + (long)(r0 + rr) * C + c0 + cc;
#pragma unroll
  for (int j = 0; j < 16; j += 4) {
    f32x4 v = *(const f32x4*)(p + j);
    tile[rr][cc + j + 0] = f2bf(v[0]);
    tile[rr][cc + j + 1] = f2bf(v[1]);
    tile[rr][cc + j + 2] = f2bf(v[2]);
    tile[rr][cc + j + 3] = f2bf(v[3]);
  }
  __syncthreads();
  int wc = t >> 2, wr = (t & 3) << 4;
  u16* q = out + (long)(c0 + wc) * R + r0 + wr;
#pragma unroll
  for (int j = 0; j < 16; ++j) q[j] = tile[wr + j][wc];
}

// ---------------- GEMM: C[M][N] = A[M][K] * Bt[N][K]^T, bf16 in, f32 acc ----------------
template <int OUTF32>
__global__ __launch_bounds__(256) void k_gemm_bt(const u16* __restrict__ A,
                                                 const u16* __restrict__ Bt,
                                                 void* __restrict__ C, int M, int N, int K) {
  __shared__ __align__(16) u16 As[128 * 32];
  __shared__ __align__(16) u16 Bs[128 * 32];
  const int t = threadIdx.x;
  const int w = t >> 6, lane = t & 63;
  const int lr = lane & 15, lg = lane >> 4;
  const int nblk = N >> 7;
  const int m0 = (int)(blockIdx.x / nblk) << 7;
  const int n0 = (int)(blockIdx.x % nblk) << 7;
  const int mw = (w >> 1) << 6, nw = (w & 1) << 6;
  f32x4 acc[4][4] = {};
  const int srow = t >> 2, sc8 = (t & 3) << 3;
  const long abase = (long)(m0 + srow) * K + sc8;
  const long bbase = (long)(n0 + srow) * K + sc8;
  for (int k0 = 0; k0 < K; k0 += 32) {
    gload16(A + abase + k0, As + t * 8);
    gload16(A + abase + 64 * (long)K + k0, As + 2048 + t * 8);
    gload16(Bt + bbase + k0, Bs + t * 8);
    gload16(Bt + bbase + 64 * (long)K + k0, Bs + 2048 + t * 8);
    __syncthreads();
    bf16x8 af[4], bfv[4];
#pragma unroll
    for (int i = 0; i < 4; ++i) {
      af[i] = *(const bf16x8*)(As + (mw + i * 16 + lr) * 32 + (lg << 3));
      bfv[i] = *(const bf16x8*)(Bs + (nw + i * 16 + lr) * 32 + (lg << 3));
    }
#pragma unroll
    for (int i = 0; i < 4; ++i)
#pragma unroll
      for (int j = 0; j < 4; ++j)
        acc[i][j] = __builtin_amdgcn_mfma_f32_16x16x32_bf16(af[i], bfv[j], acc[i][j], 0, 0, 0);
    __syncthreads();
  }
  const int crow = m0 + mw + (lg << 2);
  const int ccol = n0 + nw + lr;
#pragma unroll
  for (int i = 0; i < 4; ++i)
#pragma unroll
    for (int j = 0; j < 4; ++j) {
      long base = (long)(crow + i * 16) * N + (ccol + j * 16);
#pragma unroll
      for (int r = 0; r < 4; ++r) {
        if (OUTF32)
          ((float*)C)[base + (long)r * N] = acc[i][j][r];
        else
          ((u16*)C)[base + (long)r * N] = f2bf(acc[i][j][r]);
      }
    }
}

// ---------------- RoPE on Q: [B,S,H,HD] bf16 -> [B,H,S,HD] bf16 (scaled) ----------------
__global__ __launch_bounds__(256) void k_rope_q(const u16* __restrict__ xq,
                                                const float* __restrict__ cosp,
                                                const float* __restrict__ sinp,
                                                u16* __restrict__ qt) {
  int tid = blockIdx.x * 256 + threadIdx.x;  // b(1)|h(5)|s(11)|oct(4)
  int oct = tid & 15;
  int s = (tid >> 4) & 2047;
  int h = (tid >> 15) & 31;
  int b = tid >> 20;
  int d0 = oct << 3;
  const u16* src = xq + (((long)(b * S_ + s) * H_ + h) * HD_ + d0);
  u16x8 v = *(const u16x8*)src;
  f32x4 c = *(const f32x4*)(cosp + s * 64 + (d0 >> 1));
  f32x4 sn = *(const f32x4*)(sinp + s * 64 + (d0 >> 1));
  float o[8];
#pragma unroll
  for (int j = 0; j < 4; ++j) {
    float x1 = bf2f(v[2 * j]), x2 = bf2f(v[2 * j + 1]);
    o[2 * j] = x1 * c[j] - x2 * sn[j];
    o[2 * j + 1] = x1 * sn[j] + x2 * c[j];
  }
  u16x8 ov;
#pragma unroll
  for (int i = 0; i < 8; ++i) ov[i] = f2bf(o[i] * SCALE_);
  *(u16x8*)(qt + (long)tid * 8) = ov;
}

// ---------------- RoPE on K + fp32 cache_k ----------------
__global__ __launch_bounds__(256) void k_rope_k(const u16* __restrict__ xk,
                                                const float* __restrict__ cosp,
                                                const float* __restrict__ sinp,
                                                u16* __restrict__ kt,
                                                float* __restrict__ cache_k) {
  int tid = blockIdx.x * 256 + threadIdx.x;  // b(1)|kvh(3)|s(11)|oct(4)
  int oct = tid & 15;
  int s = (tid >> 4) & 2047;
  int kvh = (tid >> 15) & 7;
  int b = tid >> 18;
  int d0 = oct << 3;
  const u16* src = xk + (((long)(b * S_ + s) * KVH_ + kvh) * HD_ + d0);
  u16x8 v = *(const u16x8*)src;
  f32x4 c = *(const f32x4*)(cosp + s * 64 + (d0 >> 1));
  f32x4 sn = *(const f32x4*)(sinp + s * 64 + (d0 >> 1));
  float o[8];
#pragma unroll
  for (int j = 0; j < 4; ++j) {
    float x1 = bf2f(v[2 * j]), x2 = bf2f(v[2 * j + 1]);
    o[2 * j] = x1 * c[j] - x2 * sn[j];
    o[2 * j + 1] = x1 * sn[j] + x2 * c[j];
  }
  u16x8 ov;
#pragma unroll
  for (int i = 0; i < 8; ++i) ov[i] = f2bf(o[i]);
  *(u16x8*)(kt + (long)tid * 8) = ov;
  float* ck = cache_k + (((long)(b * SW_ + s) * KVH_ + kvh) * HD_ + d0);
  f32x4 f0 = {o[0], o[1], o[2], o[3]};
  f32x4 f1 = {o[4], o[5], o[6], o[7]};
  *(f32x4*)ck = f0;
  *(f32x4*)(ck + 4) = f1;
}

// ---------------- V transpose: [B,S,KVH,HD] bf16 -> [B,KVH,HD,S] bf16 + fp32 cache_v ----------------
__global__ __launch_bounds__(256) void k_transpose_v(const u16* __restrict__ xv,
                                                     u16* __restrict__ vt,
                                                     float* __restrict__ cache_v) {
  __shared__ u16 tile[64][72];
  int bid = blockIdx.x;
  int st = bid & 31;
  int dt = (bid >> 5) & 1;
  int bk = bid >> 6;  // b*8+kvh
  int t = threadIdx.x;
  int sr = t >> 2, dc = (t & 3) << 4;
  long src = ((long)(bk >> 3) * S_ + st * 64 + sr) * (KVH_ * HD_) + (bk & 7) * HD_ + dt * 64 + dc;
  u16x8 v0 = *(const u16x8*)(xv + src);
  u16x8 v1 = *(const u16x8*)(xv + src + 8);
#pragma unroll
  for (int j = 0; j < 8; ++j) {
    tile[sr][dc + j] = v0[j];
    tile[sr][dc + 8 + j] = v1[j];
  }
  long cdst = ((long)(bk >> 3) * SW_ + st * 64 + sr) * (KVH_ * HD_) + (bk & 7) * HD_ + dt * 64 + dc;
  f32x4 f0 = {bf2f(v0[0]), bf2f(v0[1]), bf2f(v0[2]), bf2f(v0[3])};
  f32x4 f1 = {bf2f(v0[4]), bf2f(v0[5]), bf2f(v0[6]), bf2f(v0[7])};
  f32x4 f2 = {bf2f(v1[0]), bf2f(v1[1]), bf2f(v1[2]), bf2f(v1[3])};
  f32x4 f3 = {bf2f(v1[4]), bf2f(v1[5]), bf2f(v1[6]), bf2f(v1[7])};
  *(f32x4*)(cache_v + cdst) = f0;
  *(f32x4*)(cache_v + cdst + 4) = f1;
  *(f32x4*)(cache_v + cdst + 8) = f2;
  *(f32x4*)(cache_v + cdst + 12) = f3;
  __syncthreads();
  int dr = t >> 2, sc = (t & 3) << 4;
  u16* q = vt + ((long)bk * HD_ + dt * 64 + dr) * S_ + st * 64 + sc;
#pragma unroll
  for (int j = 0; j < 16; ++j) q[j] = tile[sc + j][dr];
}

// ---------------- flash attention ----------------
// q_t [B,H,S,HD] (pre-scaled), k_t [B,KVH,S,HD], v_t [B,KVH,HD,S] -> attn [B,S,H*HD] bf16
__global__ __launch_bounds__(256) void k_flash(const u16* __restrict__ qt,
                                               const u16* __restrict__ kt,
                                               const u16* __restrict__ vt,
                                               u16* __restrict__ attn) {
  __shared__ __align__(16) u16 P[4][16 * 32];
  const int t = threadIdx.x, w = t >> 6, lane = t & 63;
  const int lr = lane & 15, lg = lane >> 4;
  const int qblk = blockIdx.x & 31;
  const int h = (blockIdx.x >> 5) & 31;
  const int b = blockIdx.x >> 10;
  const int kvh = h >> 2;
  const int qbase = (qblk << 6) + (w << 4);
  bf16x8 qf[4];
  const u16* qp = qt + ((long)((b * H_ + h) * S_ + qbase + lr)) * HD_ + (lg << 3);
#pragma unroll
  for (int dt = 0; dt < 4; ++dt) qf[dt] = *(const bf16x8*)(qp + dt * 32);
  f32x4 acc[8] = {};
  float m_r[4], l_r[4];
#pragma unroll
  for (int r = 0; r < 4; ++r) { m_r[r] = -1e30f; l_r[r] = 0.f; }
  const u16* kb = kt + (long)(b * KVH_ + kvh) * S_ * HD_;
  const u16* vb = vt + (long)(b * KVH_ + kvh) * HD_ * S_;
  u16* pw = &P[w][0];
  for (int kv0 = 0; kv0 < qbase + 16; kv0 += 32) {
    f32x4 s0 = {}, s1 = {};
    const u16* kp0 = kb + (long)(kv0 + lr) * HD_ + (lg << 3);
    const u16* kp1 = kp0 + 16 * HD_;
#pragma unroll
    for (int dt = 0; dt < 4; ++dt) {
      s0 = __builtin_amdgcn_mfma_f32_16x16x32_bf16(qf[dt], *(const bf16x8*)(kp0 + dt * 32), s0, 0, 0, 0);
      s1 = __builtin_amdgcn_mfma_f32_16x16x32_bf16(qf[dt], *(const bf16x8*)(kp1 + dt * 32), s1, 0, 0, 0);
    }
    if (kv0 + 31 > qbase) {
#pragma unroll
      for (int r = 0; r < 4; ++r) {
        int q = qbase + (lg << 2) + r;
        if (kv0 + lr > q) s0[r] = -1e30f;
        if (kv0 + 16 + lr > q) s1[r] = -1e30f;
      }
    }
    float corr[4];
#pragma unroll
    for (int r = 0; r < 4; ++r) {
      float mx = fmaxf(s0[r], s1[r]);
      mx = fmaxf(mx, __shfl_xor(mx, 1));
      mx = fmaxf(mx, __shfl_xor(mx, 2));
      mx = fmaxf(mx, __shfl_xor(mx, 4));
      mx = fmaxf(mx, __shfl_xor(mx, 8));
      float mnew = fmaxf(m_r[r], mx);
      corr[r] = __expf(m_r[r] - mnew);
      m_r[r] = mnew;
      float p0 = __expf(s0[r] - mnew);
      float p1 = __expf(s1[r] - mnew);
      s0[r] = p0;
      s1[r] = p1;
      float ps = p0 + p1;
      ps += __shfl_xor(ps, 1);
      ps += __shfl_xor(ps, 2);
      ps += __shfl_xor(ps, 4);
      ps += __shfl_xor(ps, 8);
      l_r[r] = l_r[r] * corr[r] + ps;
    }
#pragma unroll
    for (int dt = 0; dt < 8; ++dt)
#pragma unroll
      for (int r = 0; r < 4; ++r) acc[dt][r] *= corr[r];
#pragma unroll
    for (int r = 0; r < 4; ++r) {
      pw[((lg << 2) + r) * 32 + lr] = f2bf(s0[r]);
      pw[((lg << 2) + r) * 32 + 16 + lr] = f2bf(s1[r]);
    }
    asm volatile("s_waitcnt lgkmcnt(0)" ::: "memory");
    bf16x8 pf = *(const bf16x8*)(pw + lr * 32 + (lg << 3));
    const u16* vp = vb + (long)lr * S_ + kv0 + (lg << 3);
#pragma unroll
    for (int dt = 0; dt < 8; ++dt)
      acc[dt] = __builtin_amdgcn_mfma_f32_16x16x32_bf16(pf, *(const bf16x8*)(vp + (long)dt * 16 * S_), acc[dt], 0, 0, 0);
  }
  float inv[4];
#pragma unroll
  for (int r = 0; r < 4; ++r) inv[r] = 1.0f / l_r[r];
  u16* op = attn + (long)(b * S_ + qbase + (lg << 2)) * (H_ * HD_) + h * HD_ + lr;
#pragma unroll
  for (int dt = 0; dt < 8; ++dt)
#pragma unroll
    for (int r = 0; r < 4; ++r)
      op[(long)r * (H_ * HD_) + dt * 16] = f2bf(acc[dt][r] * inv[r]);
}

extern "C" void kernel_launch(void* const* d_in, const int* in_sizes, int n_in,
                              void* d_out, int out_size, void* d_ws, size_t ws_size,
                              hipStream_t stream) {
  (void)in_sizes; (void)n_in; (void)out_size; (void)ws_size;
  const float* x = (const float*)d_in[0];
  const float* cosp = (const float*)d_in[1];
  const float* sinp = (const float*)d_in[2];
  const float* wq = (const float*)d_in[7];
  const float* wk = (const float*)d_in[8];
  const float* wv = (const float*)d_in[9];
  const float* wo = (const float*)d_in[10];
  float* out = (float*)d_out;
  float* cko = out + 16777216;  // cache_k
  float* cvo = out + 25165824;  // cache_v
  char* ws = (char*)d_ws;
  u16* x_bf = (u16*)(ws);
  u16* wq_t = (u16*)(ws + 33554432);
  u16* wk_t = (u16*)(ws + 67108864);
  u16* wv_t = (u16*)(ws + 75497472);
  u16* wo_t = (u16*)(ws + 83886080);
  u16* xq_bf = (u16*)(ws + 117440512);
  u16* xk_bf = (u16*)(ws + 150994944);
  u16* xv_bf = (u16*)(ws + 159383552);
  u16* q_t = (u16*)(ws + 167772160);
  u16* k_t = (u16*)(ws + 201326592);
  u16* v_t = (u16*)(ws + 209715200);
  u16* attn = xq_bf;  // xq dead after rope_q; safe alias

  k_f32_to_bf16<<<8192, 256, 0, stream>>>(x, x_bf);
  k_transpose_w<<<dim3(64, 64), 256, 0, stream>>>(wq, wq_t, 4096, 4096);
  k_transpose_w<<<dim3(16, 64), 256, 0, stream>>>(wk, wk_t, 4096, 1024);
  k_transpose_w<<<dim3(16, 64), 256, 0, stream>>>(wv, wv_t, 4096, 1024);
  k_transpose_w<<<dim3(64, 64), 256, 0, stream>>>(wo, wo_t, 4096, 4096);
  k_gemm_bt<0><<<1024, 256, 0, stream>>>(x_bf, wq_t, xq_bf, 4096, 4096, 4096);
  k_gemm_bt<0><<<256, 256, 0, stream>>>(x_bf, wk_t, xk_bf, 4096, 1024, 4096);
  k_gemm_bt<0><<<256, 256, 0, stream>>>(x_bf, wv_t, xv_bf, 4096, 1024, 4096);
  k_rope_q<<<8192, 256, 0, stream>>>(xq_bf, cosp, sinp, q_t);
  k_rope_k<<<2048, 256, 0, stream>>>(xk_bf, cosp, sinp, k_t, cko);
  k_transpose_v<<<1024, 256, 0, stream>>>(xv_bf, v_t, cvo);
  hipMemsetAsync(cko + 2097152, 0, 8388608, stream);
  hipMemsetAsync(cko + 6291456, 0, 8388608, stream);
  hipMemsetAsync(cvo + 2097152, 0, 8388608, stream);
  hipMemsetAsync(cvo + 6291456, 0, 8388608, stream);
  k_flash<<<2048, 256, 0, stream>>>(q_t, k_t, v_t, attn);
  k_gemm_bt<1><<<1024, 256, 0, stream>>>(attn, wo_t, out, 4096, 4096, 4096);
}

// Round 2
// 1150.131 us; speedup vs baseline: 1.6244x; 1.6244x over previous
//
#include <hip/hip_runtime.h>

typedef __attribute__((ext_vector_type(4))) float f32x4;
typedef __attribute__((ext_vector_type(8))) __bf16 bf16x8;
typedef __attribute__((ext_vector_type(8))) unsigned short u16x8;
typedef unsigned short u16;
typedef unsigned int u32;

#define B_ 2
#define S_ 2048
#define D_ 4096
#define H_ 32
#define KVH_ 8
#define HD_ 128
#define SW_ 4096
#define SCALE_ 0.08838834764831845f

__device__ __forceinline__ u16 f2bf(float f) {
  union { float f; u32 u; } v; v.f = f;
  u32 r = v.u + 0x7FFF + ((v.u >> 16) & 1);
  return (u16)(r >> 16);
}
__device__ __forceinline__ float bf2f(u16 h) {
  union { u32 u; float f; } v; v.u = ((u32)h) << 16;
  return v.f;
}
__device__ __forceinline__ void gload16(const void* g, void* l) {
  __builtin_amdgcn_global_load_lds(
      (__attribute__((address_space(1))) u32*)(uintptr_t)g,
      (__attribute__((address_space(3))) u32*)l, 16, 0, 0);
}

// ---------------- elementwise f32 -> bf16 (8 elems/thread) ----------------
__global__ __launch_bounds__(256) void k_f32_to_bf16(const float* __restrict__ in,
                                                     u16* __restrict__ out) {
  long i = (long)(blockIdx.x * 256 + threadIdx.x) * 8;
  f32x4 a = *(const f32x4*)(in + i);
  f32x4 b = *(const f32x4*)(in + i + 4);
  u16x8 o;
  o[0] = f2bf(a[0]); o[1] = f2bf(a[1]); o[2] = f2bf(a[2]); o[3] = f2bf(a[3]);
  o[4] = f2bf(b[0]); o[5] = f2bf(b[1]); o[6] = f2bf(b[2]); o[7] = f2bf(b[3]);
  *(u16x8*)(out + i) = o;
}

// ---------------- weight transpose: [R][C] f32 -> [C][R] bf16 ----------------
__global__ __launch_bounds__(256) void k_transpose_w(const float* __restrict__ in,
                                                     u16* __restrict__ out, int R, int C) {
  __shared__ u16 tile[64][72];
  int t = threadIdx.x;
  int c0 = blockIdx.x * 64, r0 = blockIdx.y * 64;
  int rr = t >> 2, cc = (t & 3) << 4;
  const float* p = in + (long)(r0 + rr) * C + c0 + cc;
#pragma unroll
  for (int j = 0; j < 16; j += 4) {
    f32x4 v = *(const f32x4*)(p + j);
    tile[rr][cc + j + 0] = f2bf(v[0]);
    tile[rr][cc + j + 1] = f2bf(v[1]);
    tile[rr][cc + j + 2] = f2bf(v[2]);
    tile[rr][cc + j + 3] = f2bf(v[3]);
  }
  __syncthreads();
  int wc = t >> 2, wr = (t & 3) << 4;
  u16* q = out + (long)(c0 + wc) * R + r0 + wr;
#pragma unroll
  for (int j = 0; j < 16; ++j) q[j] = tile[wr + j][wc];
}

// ---------------- GEMM: C[M][N] = A[M][K] * Bt[N][K]^T, bf16 in, f32 acc ----------------
template <int OUTF32>
__global__ __launch_bounds__(256) void k_gemm_bt(const u16* __restrict__ A,
                                                 const u16* __restrict__ Bt,
                                                 void* __restrict__ C, int M, int N, int K) {
  __shared__ __align__(16) u16 As[128 * 32];
  __shared__ __align__(16) u16 Bs[128 * 32];
  const int t = threadIdx.x;
  const int w = t >> 6, lane = t & 63;
  const int lr = lane & 15, lg = lane >> 4;
  const int nblk = N >> 7;
  const int m0 = (int)(blockIdx.x / nblk) << 7;
  const int n0 = (int)(blockIdx.x % nblk) << 7;
  const int mw = (w >> 1) << 6, nw = (w & 1) << 6;
  f32x4 acc[4][4] = {};
  const int srow = t >> 2, sc8 = (t & 3) << 3;
  const long abase = (long)(m0 + srow) * K + sc8;
  const long bbase = (long)(n0 + srow) * K + sc8;
  for (int k0 = 0; k0 < K; k0 += 32) {
    gload16(A + abase + k0, As + t * 8);
    gload16(A + abase + 64 * (long)K + k0, As + 2048 + t * 8);
    gload16(Bt + bbase + k0, Bs + t * 8);
    gload16(Bt + bbase + 64 * (long)K + k0, Bs + 2048 + t * 8);
    __syncthreads();
    bf16x8 af[4], bfv[4];
#pragma unroll
    for (int i = 0; i < 4; ++i) {
      af[i] = *(const bf16x8*)(As + (mw + i * 16 + lr) * 32 + (lg << 3));
      bfv[i] = *(const bf16x8*)(Bs + (nw + i * 16 + lr) * 32 + (lg << 3));
    }
#pragma unroll
    for (int i = 0; i < 4; ++i)
#pragma unroll
      for (int j = 0; j < 4; ++j)
        acc[i][j] = __builtin_amdgcn_mfma_f32_16x16x32_bf16(af[i], bfv[j], acc[i][j], 0, 0, 0);
    __syncthreads();
  }
  const int crow = m0 + mw + (lg << 2);
  const int ccol = n0 + nw + lr;
#pragma unroll
  for (int i = 0; i < 4; ++i)
#pragma unroll
    for (int j = 0; j < 4; ++j) {
      long base = (long)(crow + i * 16) * N + (ccol + j * 16);
#pragma unroll
      for (int r = 0; r < 4; ++r) {
        if (OUTF32)
          ((float*)C)[base + (long)r * N] = acc[i][j][r];
        else
          ((u16*)C)[base + (long)r * N] = f2bf(acc[i][j][r]);
      }
    }
}

// ---------------- RoPE on Q: [B,S,H,HD] bf16 -> [B,H,S,HD] bf16 (scaled) ----------------
__global__ __launch_bounds__(256) void k_rope_q(const u16* __restrict__ xq,
                                                const float* __restrict__ cosp,
                                                const float* __restrict__ sinp,
                                                u16* __restrict__ qt) {
  int tid = blockIdx.x * 256 + threadIdx.x;  // b(1)|h(5)|s(11)|oct(4)
  int oct = tid & 15;
  int s = (tid >> 4) & 2047;
  int h = (tid >> 15) & 31;
  int b = tid >> 20;
  int d0 = oct << 3;
  const u16* src = xq + (((long)(b * S_ + s) * H_ + h) * HD_ + d0);
  u16x8 v = *(const u16x8*)src;
  f32x4 c = *(const f32x4*)(cosp + s * 64 + (d0 >> 1));
  f32x4 sn = *(const f32x4*)(sinp + s * 64 + (d0 >> 1));
  float o[8];
#pragma unroll
  for (int j = 0; j < 4; ++j) {
    float x1 = bf2f(v[2 * j]), x2 = bf2f(v[2 * j + 1]);
    o[2 * j] = x1 * c[j] - x2 * sn[j];
    o[2 * j + 1] = x1 * sn[j] + x2 * c[j];
  }
  u16x8 ov;
#pragma unroll
  for (int i = 0; i < 8; ++i) ov[i] = f2bf(o[i] * SCALE_);
  *(u16x8*)(qt + (long)tid * 8) = ov;
}

// ---------------- RoPE on K + fp32 cache_k ----------------
__global__ __launch_bounds__(256) void k_rope_k(const u16* __restrict__ xk,
                                                const float* __restrict__ cosp,
                                                const float* __restrict__ sinp,
                                                u16* __restrict__ kt,
                                                float* __restrict__ cache_k) {
  int tid = blockIdx.x * 256 + threadIdx.x;  // b(1)|kvh(3)|s(11)|oct(4)
  int oct = tid & 15;
  int s = (tid >> 4) & 2047;
  int kvh = (tid >> 15) & 7;
  int b = tid >> 18;
  int d0 = oct << 3;
  const u16* src = xk + (((long)(b * S_ + s) * KVH_ + kvh) * HD_ + d0);
  u16x8 v = *(const u16x8*)src;
  f32x4 c = *(const f32x4*)(cosp + s * 64 + (d0 >> 1));
  f32x4 sn = *(const f32x4*)(sinp + s * 64 + (d0 >> 1));
  float o[8];
#pragma unroll
  for (int j = 0; j < 4; ++j) {
    float x1 = bf2f(v[2 * j]), x2 = bf2f(v[2 * j + 1]);
    o[2 * j] = x1 * c[j] - x2 * sn[j];
    o[2 * j + 1] = x1 * sn[j] + x2 * c[j];
  }
  u16x8 ov;
#pragma unroll
  for (int i = 0; i < 8; ++i) ov[i] = f2bf(o[i]);
  *(u16x8*)(kt + (long)tid * 8) = ov;
  float* ck = cache_k + (((long)(b * SW_ + s) * KVH_ + kvh) * HD_ + d0);
  f32x4 f0 = {o[0], o[1], o[2], o[3]};
  f32x4 f1 = {o[4], o[5], o[6], o[7]};
  *(f32x4*)ck = f0;
  *(f32x4*)(ck + 4) = f1;
}

// ---------------- V transpose: [B,S,KVH,HD] bf16 -> [B,KVH,HD,S] bf16 + fp32 cache_v ----------------
__global__ __launch_bounds__(256) void k_transpose_v(const u16* __restrict__ xv,
                                                     u16* __restrict__ vt,
                                                     float* __restrict__ cache_v) {
  __shared__ u16 tile[64][72];
  int bid = blockIdx.x;
  int st = bid & 31;
  int dt = (bid >> 5) & 1;
  int bk = bid >> 6;  // b*8+kvh
  int t = threadIdx.x;
  int sr = t >> 2, dc = (t & 3) << 4;
  long src = ((long)(bk >> 3) * S_ + st * 64 + sr) * (KVH_ * HD_) + (bk & 7) * HD_ + dt * 64 + dc;
  u16x8 v0 = *(const u16x8*)(xv + src);
  u16x8 v1 = *(const u16x8*)(xv + src + 8);
#pragma unroll
  for (int j = 0; j < 8; ++j) {
    tile[sr][dc + j] = v0[j];
    tile[sr][dc + 8 + j] = v1[j];
  }
  long cdst = ((long)(bk >> 3) * SW_ + st * 64 + sr) * (KVH_ * HD_) + (bk & 7) * HD_ + dt * 64 + dc;
  f32x4 f0 = {bf2f(v0[0]), bf2f(v0[1]), bf2f(v0[2]), bf2f(v0[3])};
  f32x4 f1 = {bf2f(v0[4]), bf2f(v0[5]), bf2f(v0[6]), bf2f(v0[7])};
  f32x4 f2 = {bf2f(v1[0]), bf2f(v1[1]), bf2f(v1[2]), bf2f(v1[3])};
  f32x4 f3 = {bf2f(v1[4]), bf2f(v1[5]), bf2f(v1[6]), bf2f(v1[7])};
  *(f32x4*)(cache_v + cdst) = f0;
  *(f32x4*)(cache_v + cdst + 4) = f1;
  *(f32x4*)(cache_v + cdst + 8) = f2;
  *(f32x4*)(cache_v + cdst + 12) = f3;
  __syncthreads();
  int dr = t >> 2, sc = (t & 3) << 4;
  u16* q = vt + ((long)bk * HD_ + dt * 64 + dr) * S_ + st * 64 + sc;
#pragma unroll
  for (int j = 0; j < 16; ++j) q[j] = tile[sc + j][dr];
}

// ---------------- flash attention v2: LDS-staged K/V, swizzled, 128 q-rows/block ---------
// q_t [B,H,S,HD] (pre-scaled), k_t [B,KVH,S,HD], v_t [B,KVH,HD,S] -> attn [B,S,H*HD] bf16
__global__ __launch_bounds__(256) void k_flash2(const u16* __restrict__ qt_,
                                                const u16* __restrict__ kt,
                                                const u16* __restrict__ vt,
                                                u16* __restrict__ attn) {
  __shared__ __align__(16) u16 Ks[8192];        // 64 kv x 128 d, swizzled
  __shared__ __align__(16) u16 Vs[8192];        // 128 d x 64 kv (V^T), swizzled
  __shared__ __align__(16) u16 Ps[4][32 * 72];  // per-wave P tile, padded stride 72
  const int t = threadIdx.x, w = t >> 6, lane = t & 63;
  const int lr = lane & 15, lg = lane >> 4;
  const int bid = blockIdx.x;
  const int qtile = 15 - (bid >> 6);  // heavy blocks first (LPT)
  const int bh = bid & 63;
  const int b = bh >> 5, h = bh & 31;
  const int kvh = h >> 2;
  const int q0 = qtile << 7;
  const int q_w = q0 + (w << 5);
  const u16* qb = qt_ + (long)(b * H_ + h) * S_ * HD_;
  const u16* kb = kt + (long)(b * KVH_ + kvh) * S_ * HD_;
  const u16* vb = vt + (long)(b * KVH_ + kvh) * HD_ * S_;
  // Q fragments: 32 q-rows per wave, resident in regs
  bf16x8 qf[2][4];
#pragma unroll
  for (int mf = 0; mf < 2; ++mf)
#pragma unroll
    for (int ks = 0; ks < 4; ++ks)
      qf[mf][ks] = *(const bf16x8*)(qb + (long)(q_w + mf * 16 + lr) * HD_ + ks * 32 + (lg << 3));
  f32x4 acc[2][8] = {};
  float m_[2][4], l_[2][4];
#pragma unroll
  for (int mf = 0; mf < 2; ++mf)
#pragma unroll
    for (int r = 0; r < 4; ++r) { m_[mf][r] = -1e30f; l_[mf][r] = 0.f; }
  const int ntiles = 2 * qtile + 2;
  for (int it = 0; it < ntiles; ++it) {
    const int kv0 = it << 6;
    __syncthreads();  // prev-tile LDS reads complete before overwrite
    // stage K: LDS linear dest, inverse-swizzled global source (rule #21)
#pragma unroll
    for (int ci = 0; ci < 4; ++ci) {
      int r = ci * 16 + (t >> 4);
      gload16(kb + (long)(kv0 + r) * HD_ + (((t & 15) ^ (r & 15)) << 3),
              Ks + ci * 2048 + t * 8);
    }
#pragma unroll
    for (int ci = 0; ci < 4; ++ci) {
      int d = ci * 32 + (t >> 3);
      gload16(vb + (long)d * S_ + kv0 + (((t & 7) ^ (d & 7)) << 3),
              Vs + ci * 2048 + t * 8);
    }
    __syncthreads();  // drains vmcnt before barrier (compiler-emitted)
    // ---- QK^T ----
    f32x4 s[2][4] = {};
#pragma unroll
    for (int ks = 0; ks < 4; ++ks) {
      bf16x8 kf4[4];
#pragma unroll
      for (int kf = 0; kf < 4; ++kf) {
        int r = kf * 16 + lr;
        kf4[kf] = *(const bf16x8*)(Ks + r * 128 + (((ks * 4 + lg) ^ (r & 15)) << 3));
      }
#pragma unroll
      for (int mf = 0; mf < 2; ++mf)
#pragma unroll
        for (int kf = 0; kf < 4; ++kf)
          s[mf][kf] = __builtin_amdgcn_mfma_f32_16x16x32_bf16(qf[mf][ks], kf4[kf], s[mf][kf], 0, 0, 0);
    }
    // ---- causal mask ----
    if (kv0 + 63 > q_w) {
#pragma unroll
      for (int mf = 0; mf < 2; ++mf)
#pragma unroll
        for (int kf = 0; kf < 4; ++kf)
#pragma unroll
          for (int r = 0; r < 4; ++r)
            if (kv0 + kf * 16 + lr > q_w + mf * 16 + (lg << 2) + r) s[mf][kf][r] = -1e30f;
    }
    // ---- online softmax (reduce across 16 lr lanes) + P write + acc rescale ----
#pragma unroll
    for (int mf = 0; mf < 2; ++mf)
#pragma unroll
      for (int r = 0; r < 4; ++r) {
        float t0 = fmaxf(fmaxf(s[mf][0][r], s[mf][1][r]), fmaxf(s[mf][2][r], s[mf][3][r]));
        t0 = fmaxf(t0, __shfl_xor(t0, 1));
        t0 = fmaxf(t0, __shfl_xor(t0, 2));
        t0 = fmaxf(t0, __shfl_xor(t0, 4));
        t0 = fmaxf(t0, __shfl_xor(t0, 8));
        float mn = fmaxf(m_[mf][r], t0);
        float corr = __expf(m_[mf][r] - mn);
        m_[mf][r] = mn;
        float p0 = __expf(s[mf][0][r] - mn);
        float p1 = __expf(s[mf][1][r] - mn);
        float p2 = __expf(s[mf][2][r] - mn);
        float p3 = __expf(s[mf][3][r] - mn);
        float ts = (p0 + p1) + (p2 + p3);
        ts += __shfl_xor(ts, 1);
        ts += __shfl_xor(ts, 2);
        ts += __shfl_xor(ts, 4);
        ts += __shfl_xor(ts, 8);
        l_[mf][r] = l_[mf][r] * corr + ts;
        u16* pw = &Ps[w][(mf * 16 + (lg << 2) + r) * 72];
        pw[lr] = f2bf(p0);
        pw[16 + lr] = f2bf(p1);
        pw[32 + lr] = f2bf(p2);
        pw[48 + lr] = f2bf(p3);
#pragma unroll
        for (int df = 0; df < 8; ++df) acc[mf][df][r] *= corr;
      }
    asm volatile("s_waitcnt lgkmcnt(0)" ::: "memory");
    // ---- PV ----
#pragma unroll
    for (int ks2 = 0; ks2 < 2; ++ks2) {
      bf16x8 pf[2];
#pragma unroll
      for (int mf = 0; mf < 2; ++mf)
        pf[mf] = *(const bf16x8*)(&Ps[w][(mf * 16 + lr) * 72 + ks2 * 32 + (lg << 3)]);
#pragma unroll
      for (int df = 0; df < 8; ++df) {
        int d = df * 16 + lr;
        bf16x8 vf = *(const bf16x8*)(Vs + d * 64 + (((ks2 * 4 + lg) ^ (d & 7)) << 3));
#pragma unroll
        for (int mf = 0; mf < 2; ++mf)
          acc[mf][df] = __builtin_amdgcn_mfma_f32_16x16x32_bf16(pf[mf], vf, acc[mf][df], 0, 0, 0);
      }
    }
  }
  // ---- epilogue ----
#pragma unroll
  for (int mf = 0; mf < 2; ++mf)
#pragma unroll
    for (int r = 0; r < 4; ++r) {
      float inv = 1.0f / l_[mf][r];
      u16* op = attn + (long)(b * S_ + q_w + mf * 16 + (lg << 2) + r) * (H_ * HD_) + h * HD_ + lr;
#pragma unroll
      for (int df = 0; df < 8; ++df) op[df * 16] = f2bf(acc[mf][df][r] * inv);
    }
}

extern "C" void kernel_launch(void* const* d_in, const int* in_sizes, int n_in,
                              void* d_out, int out_size, void* d_ws, size_t ws_size,
                              hipStream_t stream) {
  (void)in_sizes; (void)n_in; (void)out_size; (void)ws_size;
  const float* x = (const float*)d_in[0];
  const float* cosp = (const float*)d_in[1];
  const float* sinp = (const float*)d_in[2];
  const float* wq = (const float*)d_in[7];
  const float* wk = (const float*)d_in[8];
  const float* wv = (const float*)d_in[9];
  const float* wo = (const float*)d_in[10];
  float* out = (float*)d_out;
  float* cko = out + 16777216;  // cache_k
  float* cvo = out + 25165824;  // cache_v
  char* ws = (char*)d_ws;
  u16* x_bf = (u16*)(ws);
  u16* wq_t = (u16*)(ws + 33554432);
  u16* wk_t = (u16*)(ws + 67108864);
  u16* wv_t = (u16*)(ws + 75497472);
  u16* wo_t = (u16*)(ws + 83886080);
  u16* xq_bf = (u16*)(ws + 117440512);
  u16* xk_bf = (u16*)(ws + 150994944);
  u16* xv_bf = (u16*)(ws + 159383552);
  u16* q_t = (u16*)(ws + 167772160);
  u16* k_t = (u16*)(ws + 201326592);
  u16* v_t = (u16*)(ws + 209715200);
  u16* attn = xq_bf;  // xq dead after rope_q; safe alias

  k_f32_to_bf16<<<8192, 256, 0, stream>>>(x, x_bf);
  k_transpose_w<<<dim3(64, 64), 256, 0, stream>>>(wq, wq_t, 4096, 4096);
  k_transpose_w<<<dim3(16, 64), 256, 0, stream>>>(wk, wk_t, 4096, 1024);
  k_transpose_w<<<dim3(16, 64), 256, 0, stream>>>(wv, wv_t, 4096, 1024);
  k_transpose_w<<<dim3(64, 64), 256, 0, stream>>>(wo, wo_t, 4096, 4096);
  k_gemm_bt<0><<<1024, 256, 0, stream>>>(x_bf, wq_t, xq_bf, 4096, 4096, 4096);
  k_gemm_bt<0><<<256, 256, 0, stream>>>(x_bf, wk_t, xk_bf, 4096, 1024, 4096);
  k_gemm_bt<0><<<256, 256, 0, stream>>>(x_bf, wv_t, xv_bf, 4096, 1024, 4096);
  k_rope_q<<<8192, 256, 0, stream>>>(xq_bf, cosp, sinp, q_t);
  k_rope_k<<<2048, 256, 0, stream>>>(xk_bf, cosp, sinp, k_t, cko);
  k_transpose_v<<<1024, 256, 0, stream>>>(xv_bf, v_t, cvo);
  hipMemsetAsync(cko + 2097152, 0, 8388608, stream);
  hipMemsetAsync(cko + 6291456, 0, 8388608, stream);
  hipMemsetAsync(cvo + 2097152, 0, 8388608, stream);
  hipMemsetAsync(cvo + 6291456, 0, 8388608, stream);
  k_flash2<<<1024, 256, 0, stream>>>(q_t, k_t, v_t, attn);
  k_gemm_bt<1><<<1024, 256, 0, stream>>>(attn, wo_t, out, 4096, 4096, 4096);
}